// Round 8
// baseline (12300.043 us; speedup 1.0000x reference)
//
#include <hip/hip_runtime.h>
#include <math.h>

typedef __bf16 bf16;
typedef unsigned short u16;

#define T_SEQ 2048
#define NB    2
#define CE    512
#define NH    8
#define HD    64
#define ROWS  4096
#define NBH   16

// =====================================================================
// Sniffer: flags[0]=1 if float inputs are fp32 storage (raw or rounded);
//          flags[1]=1 if tokens are int64
// =====================================================================
__global__ __launch_bounds__(256) void sniff(const u16* __restrict__ xs,
                                             const int* __restrict__ toks,
                                             int* __restrict__ flags)
{
  const int tid = threadIdx.x;
  int crazy = 0, ze = 0;
  for (int i = tid; i < 4096; i += 256) {
    int e = (xs[i] >> 7) & 0xFF;
    if (e >= 141) crazy++;                    // impossible for bf16 N(0,1)
    if (((i & 1) == 0) && (xs[i] == 0)) ze++; // fp32 low-half exactly zero
  }
  int zc = 0;
  for (int i = tid; i < 1024; i += 256)
    if (toks[2 * i + 1] == 0) zc++;           // int64 high words are 0
  __shared__ int r1[4], r2[4], r3[4];
#pragma unroll
  for (int o = 32; o; o >>= 1) {
    crazy += __shfl_down(crazy, o); ze += __shfl_down(ze, o); zc += __shfl_down(zc, o);
  }
  if ((tid & 63) == 0) { r1[tid >> 6] = crazy; r2[tid >> 6] = ze; r3[tid >> 6] = zc; }
  __syncthreads();
  if (tid == 0) {
    int c = r1[0] + r1[1] + r1[2] + r1[3];
    int z = r2[0] + r2[1] + r2[2] + r2[3];
    int t = r3[0] + r3[1] + r3[2] + r3[3];
    flags[0] = (z > 1500 || c > 64) ? 1 : 0;
    flags[1] = (t > 900) ? 1 : 0;
  }
}

static __device__ __forceinline__ float ldf(const void* src, size_t eoff, bool f32) {
  return f32 ? ((const float*)src)[eoff] : (float)((const bf16*)src)[eoff];
}

// =====================================================================
// Positional embedding: xf = x + pe (fp32 only)
// =====================================================================
__global__ __launch_bounds__(256) void posembed(const void* __restrict__ xsrc,
                                                const int* __restrict__ toks,
                                                const int* __restrict__ flags,
                                                float* __restrict__ xf)
{
  const bool f32 = flags[0] != 0;
  const bool tok64 = flags[1] != 0;
  const int row = blockIdx.x;
  const int t = row >> 1, b = row & 1;
  const int tix = b * T_SEQ + t;
  const int tok = tok64 ? toks[2 * tix] : toks[tix];
  const int p = (tok != 0) ? (t + 1) : 0;
  const float kf = -0.0361193740f; // -ln(10000)/255
  for (int c = threadIdx.x; c < CE; c += 256) {
    float pe = 0.0f;
    if (p != 0) {
      int i = (c < 256) ? c : (c - 256);
      float freq = expf((float)i * kf);
      float ang = (float)p * freq;
      pe = (c < 256) ? sinf(ang) : cosf(ang);
    }
    xf[(size_t)row * CE + c] = ldf(xsrc, (size_t)row * CE + c, f32) + pe;
  }
}

// =====================================================================
// Naive fp32 GEMM: C[M,N] = A[M,K]*W[N,K]^T + bias (+relu), fp32 out.
// A: fp32 ws buffer (a_inp=0) or raw input (a_inp=1, dtype by flag).
// =====================================================================
template<bool RELUF>
__global__ __launch_bounds__(256) void gemm32(const void* __restrict__ A, int a_inp,
                                              const void* __restrict__ Bw, size_t bwOff,
                                              const void* __restrict__ bias, size_t biasOff,
                                              const int* __restrict__ flags,
                                              float* __restrict__ Cf,
                                              int M, int N, int K)
{
  __shared__ float As[64 * 17];
  __shared__ float Bs[64 * 17];
  const int fl = flags[0];
  const bool a_f32 = (a_inp == 0) ? true : (fl != 0);
  const bool b_f32 = (fl != 0);
  const int tid = threadIdx.x;
  const int m0 = blockIdx.y * 64, n0 = blockIdx.x * 64;
  const int tr = tid >> 4, tc = tid & 15;
  float acc[4][4] = {};
  const int sr = tid >> 2, sc4 = (tid & 3) * 4;
  for (int k0 = 0; k0 < K; k0 += 16) {
    __syncthreads();
#pragma unroll
    for (int j = 0; j < 4; j++) {
      As[sr * 17 + sc4 + j] = ldf(A,  (size_t)(m0 + sr) * K + k0 + sc4 + j, a_f32);
      Bs[sr * 17 + sc4 + j] = ldf(Bw, bwOff + (size_t)(n0 + sr) * K + k0 + sc4 + j, b_f32);
    }
    __syncthreads();
#pragma unroll
    for (int k = 0; k < 16; k++) {
      float a4[4], b4[4];
#pragma unroll
      for (int i = 0; i < 4; i++) a4[i] = As[(tr * 4 + i) * 17 + k];
#pragma unroll
      for (int j = 0; j < 4; j++) b4[j] = Bs[(tc * 4 + j) * 17 + k];
#pragma unroll
      for (int i = 0; i < 4; i++)
#pragma unroll
        for (int j = 0; j < 4; j++)
          acc[i][j] += a4[i] * b4[j];
    }
  }
#pragma unroll
  for (int j = 0; j < 4; j++) {
    int col = n0 + tc * 4 + j;
    float bv = ldf(bias, biasOff + col, b_f32);
#pragma unroll
    for (int i = 0; i < 4; i++) {
      int row = m0 + tr * 4 + i;
      float v = acc[i][j] + bv;
      if (RELUF) v = fmaxf(v, 0.0f);
      Cf[(size_t)row * N + col] = v;
    }
  }
}

// =====================================================================
// Min/max pass: direct scores from projection layout; masked entries are
// explicit zeros (exactly mirrors w*mask). partial[2*bidx] = {min,max}.
// =====================================================================
template<bool MASK>
__global__ __launch_bounds__(256) void mm_direct(const float* __restrict__ qbase, int qld, int qofs0,
                                                 const float* __restrict__ kbase, int kld, int kofs0,
                                                 float* __restrict__ partial)
{
  const int bh = blockIdx.x, t0 = blockIdx.y * 64;
  const int b = bh >> 3, h = bh & 7;
  const int qofs = qofs0 + h * HD, kofs = kofs0 + h * HD;
  __shared__ float qs[64 * 68];
  __shared__ float ks[64 * 68];
  const int tid = threadIdx.x;
#pragma unroll
  for (int it = 0; it < 16; it++) {
    int idx = it * 256 + tid, r = idx >> 6, d = idx & 63;
    qs[r * 68 + d] = qbase[(size_t)((t0 + r) * NB + b) * qld + qofs + d] * 0.125f;
  }
  float mn = 1e30f, mx = -1e30f;
  const int send = MASK ? (t0 + 64) : T_SEQ;
  const int t = tid & 63, sg = tid >> 6;
  for (int s0 = 0; s0 < send; s0 += 64) {
    __syncthreads();
#pragma unroll
    for (int it = 0; it < 16; it++) {
      int idx = it * 256 + tid, r = idx >> 6, d = idx & 63;
      ks[r * 68 + d] = kbase[(size_t)((s0 + r) * NB + b) * kld + kofs + d];
    }
    __syncthreads();
    for (int si = 0; si < 16; si++) {
      int sl = sg * 16 + si, s = s0 + sl;
      float dot = 0.f;
#pragma unroll 8
      for (int d = 0; d < 64; d++) dot += qs[t * 68 + d] * ks[sl * 68 + d];
      float wm = (MASK && s > t0 + t) ? 0.0f : dot;  // w * tril: masked -> exact 0
      mn = fminf(mn, wm); mx = fmaxf(mx, wm);
    }
  }
  __shared__ float rn[4], rx[4];
  const int w = tid >> 6, l = tid & 63;
#pragma unroll
  for (int o = 32; o; o >>= 1) { mn = fminf(mn, __shfl_down(mn, o)); mx = fmaxf(mx, __shfl_down(mx, o)); }
  if (l == 0) { rn[w] = mn; rx[w] = mx; }
  __syncthreads();
  if (tid == 0) {
    int bidx = blockIdx.y * NBH + blockIdx.x;
    partial[2 * bidx]     = fminf(fminf(rn[0], rn[1]), fminf(rn[2], rn[3]));
    partial[2 * bidx + 1] = fmaxf(fmaxf(rx[0], rx[1]), fmaxf(rx[2], rx[3]));
  }
}

// reduce 512 partial pairs -> mmf
__global__ __launch_bounds__(512) void reduce_mm(const float* __restrict__ partial,
                                                 float* __restrict__ mmf)
{
  const int tid = threadIdx.x, w = tid >> 6, l = tid & 63;
  __shared__ float rn[8], rx[8];
  float mn = partial[2 * tid], mx = partial[2 * tid + 1];
#pragma unroll
  for (int o = 32; o; o >>= 1) { mn = fminf(mn, __shfl_down(mn, o)); mx = fmaxf(mx, __shfl_down(mx, o)); }
  if (l == 0) { rn[w] = mn; rx[w] = mx; }
  __syncthreads();
  if (tid == 0) {
    float a = 1e30f, c = -1e30f;
#pragma unroll
    for (int i = 0; i < 8; i++) { a = fminf(a, rn[i]); c = fmaxf(c, rx[i]); }
    mmf[0] = a; mmf[1] = c;
  }
}

// =====================================================================
// Apply pass (direct): w' = (w_m - mn)*inv for EVERY s (incl. masked),
// out = sum_s w' * v.  No affine trick, fp32 throughout.
// =====================================================================
template<bool MASK>
__global__ __launch_bounds__(256) void attn_direct(const float* __restrict__ qbase, int qld, int qofs0,
                                                   const float* __restrict__ kbase, int kld, int kofs0,
                                                   int vofs0,
                                                   const float* __restrict__ mmf,
                                                   float* __restrict__ aout)
{
  const int bh = blockIdx.x, t0 = blockIdx.y * 32;
  const int b = bh >> 3, h = bh & 7;
  const int qofs = qofs0 + h * HD, kofs = kofs0 + h * HD, vofs = vofs0 + h * HD;
  __shared__ float qs[32 * 68];
  __shared__ float ks[64 * 68];
  __shared__ float vs[64 * 68];
  __shared__ float sc[32 * 68];
  const int tid = threadIdx.x;
  const float mn = mmf[0];
  const float inv = 1.0f / (mmf[1] - mmf[0]);
#pragma unroll
  for (int it = 0; it < 8; it++) {
    int idx = it * 256 + tid, r = idx >> 6, d = idx & 63;
    qs[r * 68 + d] = qbase[(size_t)((t0 + r) * NB + b) * qld + qofs + d] * 0.125f;
  }
  float accO[8] = {};
  const int tS = tid & 31, sg = tid >> 5;
  for (int s0 = 0; s0 < T_SEQ; s0 += 64) {   // ALL s — masked entries contribute (0-mn)*inv
    __syncthreads();
#pragma unroll
    for (int it = 0; it < 16; it++) {
      int idx = it * 256 + tid, r = idx >> 6, d = idx & 63;
      size_t rowb = (size_t)((s0 + r) * NB + b) * kld;
      ks[r * 68 + d] = kbase[rowb + kofs + d];
      vs[r * 68 + d] = kbase[rowb + vofs + d];
    }
    __syncthreads();
    for (int si = 0; si < 8; si++) {
      int sl = sg * 8 + si, s = s0 + sl;
      float dot = 0.f;
#pragma unroll 8
      for (int d = 0; d < 64; d++) dot += qs[tS * 68 + d] * ks[sl * 68 + d];
      float wm = (MASK && s > t0 + tS) ? 0.0f : dot;
      sc[tS * 68 + sl] = (wm - mn) * inv;    // explicit normalization of every entry
    }
    __syncthreads();
    for (int sl = 0; sl < 64; sl++) {
      float p = sc[tS * 68 + sl];
#pragma unroll
      for (int j = 0; j < 8; j++) accO[j] += p * vs[sl * 68 + sg * 8 + j];
    }
  }
#pragma unroll
  for (int j = 0; j < 8; j++)
    aout[(size_t)((t0 + tS) * NB + b) * CE + h * HD + sg * 8 + j] = accO[j];
}

// =====================================================================
// LayerNorm(res + y), all fp32; g/b raw inputs (dtype by flag)
// =====================================================================
__global__ __launch_bounds__(256) void ln32(const float* res, const float* yy,
                                            const void* __restrict__ g, const void* __restrict__ be,
                                            size_t goff, const int* __restrict__ flags,
                                            float* xfo)
{
  __shared__ float red[4];
  const bool fl = flags[0] != 0;
  const int tid = threadIdx.x;
  const size_t base = (size_t)blockIdx.x * CE;
  float a  = res[base + tid] + yy[base + tid];
  float b2 = res[base + tid + 256] + yy[base + tid + 256];
  float s = a + b2;
#pragma unroll
  for (int o = 32; o; o >>= 1) s += __shfl_down(s, o);
  if ((tid & 63) == 0) red[tid >> 6] = s;
  __syncthreads();
  float mu = (red[0] + red[1] + red[2] + red[3]) * (1.0f / 512.0f);
  __syncthreads();
  float da = a - mu, db = b2 - mu;
  float q = da * da + db * db;
#pragma unroll
  for (int o = 32; o; o >>= 1) q += __shfl_down(q, o);
  if ((tid & 63) == 0) red[tid >> 6] = q;
  __syncthreads();
  float var = (red[0] + red[1] + red[2] + red[3]) * (1.0f / 512.0f);
  float rs = rsqrtf(var + 1e-20f);
  xfo[base + tid]       = da * rs * ldf(g, goff + tid, fl)       + ldf(be, goff + tid, fl);
  xfo[base + tid + 256] = db * rs * ldf(g, goff + tid + 256, fl) + ldf(be, goff + tid + 256, fl);
}

// =====================================================================
extern "C" void kernel_launch(void* const* d_in, const int* in_sizes, int n_in,
                              void* d_out, int out_size, void* d_ws, size_t ws_size,
                              hipStream_t stream)
{
  (void)in_sizes; (void)n_in; (void)out_size; (void)ws_size;
  // dict order (confirmed: in_sizes[0] == 2097152 = x)
  const void* x_in   = d_in[0];
  const void* enc_in = d_in[1];
  const int*  tokens = (const int*)d_in[2];
  const void* sWqkv = d_in[3];
  const void* sbqkv = d_in[4];
  const void* sWo   = d_in[5];
  const void* sbo   = d_in[6];
  const void* cWqkv = d_in[7];
  const void* cbqkv = d_in[8];
  const void* cWo   = d_in[9];
  const void* cbo   = d_in[10];
  const void* fc1w  = d_in[11];
  const void* fc1b  = d_in[12];
  const void* fc2w  = d_in[13];
  const void* fc2b  = d_in[14];
  const void* ln1g  = d_in[15];
  const void* ln1b  = d_in[16];
  const void* ln2g  = d_in[17];
  const void* ln2b  = d_in[18];
  const void* ln3g  = d_in[19];
  const void* ln3b  = d_in[20];

  char* ws = (char*)d_ws;
  size_t off = 0;
  auto alloc = [&](size_t bytes) -> char* {
    char* p = ws + off;
    off += (bytes + 255) & ~(size_t)255;
    return p;
  };
  // total ~40.3 MiB (proven-finite footprint)
  int*   flags   = (int*)  alloc(256);
  float* mmf     = (float*)alloc(256);
  float* partial = (float*)alloc(4096);
  float* xf      = (float*)alloc((size_t)ROWS * CE * 4);      //  8 MiB residual / x
  float* y       = (float*)alloc((size_t)ROWS * CE * 4);      //  8 MiB attn-out / ffn-out
  float* qkv     = (float*)alloc((size_t)ROWS * 1536 * 4);    // 24 MiB projections / h
  float* kvb = qkv + (size_t)ROWS * 512;

  sniff<<<1, 256, 0, stream>>>((const u16*)x_in, tokens, flags);
  posembed<<<ROWS, 256, 0, stream>>>(x_in, tokens, flags, xf);

  for (int l = 0; l < 4; l++) {
    // ---------------- self-attention ----------------
    gemm32<false><<<dim3(24, 64), 256, 0, stream>>>(
        xf, 0, sWqkv, (size_t)l * 1536 * 512, sbqkv, (size_t)l * 1536, flags, qkv, ROWS, 1536, 512);
    mm_direct<true><<<dim3(NBH, 32), 256, 0, stream>>>(qkv, 1536, 0, qkv, 1536, 512, partial);
    reduce_mm<<<1, 512, 0, stream>>>(partial, mmf);
    attn_direct<true><<<dim3(NBH, 64), 256, 0, stream>>>(qkv, 1536, 0, qkv, 1536, 512, 1024, mmf, y);
    gemm32<false><<<dim3(8, 64), 256, 0, stream>>>(
        y, 0, sWo, (size_t)l * 512 * 512, sbo, (size_t)l * 512, flags, qkv, ROWS, 512, 512);
    ln32<<<ROWS, 256, 0, stream>>>(xf, qkv, ln1g, ln1b, (size_t)l * 512, flags, xf);

    // ---------------- cross-attention ----------------
    gemm32<false><<<dim3(8, 64), 256, 0, stream>>>(
        xf, 0, cWqkv, (size_t)l * 1536 * 512, cbqkv, (size_t)l * 1536, flags, qkv, ROWS, 512, 512);
    gemm32<false><<<dim3(16, 64), 256, 0, stream>>>(
        enc_in, 1, cWqkv, (size_t)l * 1536 * 512 + (size_t)512 * 512, cbqkv, (size_t)l * 1536 + 512,
        flags, kvb, ROWS, 1024, 512);
    mm_direct<false><<<dim3(NBH, 32), 256, 0, stream>>>(qkv, 512, 0, kvb, 1024, 0, partial);
    reduce_mm<<<1, 512, 0, stream>>>(partial, mmf);
    attn_direct<false><<<dim3(NBH, 64), 256, 0, stream>>>(qkv, 512, 0, kvb, 1024, 0, 512, mmf, y);
    gemm32<false><<<dim3(8, 64), 256, 0, stream>>>(
        y, 0, cWo, (size_t)l * 512 * 512, cbo, (size_t)l * 512, flags, qkv, ROWS, 512, 512);
    ln32<<<ROWS, 256, 0, stream>>>(xf, qkv, ln2g, ln2b, (size_t)l * 512, flags, xf);

    // ---------------- FFN (two row-halves; h = 16 MiB in qkv) ----------------
    for (int half = 0; half < 2; half++) {
      const float* Ain = xf + (size_t)half * 2048 * 512;
      float* yout = y + (size_t)half * 2048 * 512;
      gemm32<true><<<dim3(32, 32), 256, 0, stream>>>(
          Ain, 0, fc1w, (size_t)l * 2048 * 512, fc1b, (size_t)l * 2048, flags, qkv, 2048, 2048, 512);
      gemm32<false><<<dim3(8, 32), 256, 0, stream>>>(
          qkv, 0, fc2w, (size_t)l * 512 * 2048, fc2b, (size_t)l * 512, flags, yout, 2048, 512, 2048);
    }
    // last layer writes fp32 straight to d_out (reference output dtype = float32)
    float* lnout = (l == 3) ? (float*)d_out : xf;
    ln32<<<ROWS, 256, 0, stream>>>(xf, y, ln3g, ln3b, (size_t)l * 512, flags, lnout);
  }
}